// Round 11
// baseline (293.455 us; speedup 1.0000x reference)
//
#include <hip/hip_runtime.h>
#include <hip/hip_bf16.h>
#include <stdint.h>

#define Bb 16
#define Nn 1024
#define Hh 8
#define Dd 64

typedef unsigned short u16;
typedef float f32x4 __attribute__((ext_vector_type(4)));
typedef short short8 __attribute__((ext_vector_type(8)));

union U4S8 { uint4 u; short8 s; };
union BF2U { __hip_bfloat162 h; uint32_t u; };

__device__ __forceinline__ uint32_t packbf2(float lo, float hi){
  BF2U t; t.h = __float22bfloat162_rn(make_float2(lo, hi));
  return t.u;      // v_cvt_pk_bf16_f32: 1 instr vs ~7 for manual round+or
}

__device__ __forceinline__ f32x4 mfma16(short8 a, short8 b, f32x4 c){
  return __builtin_amdgcn_mfma_f32_16x16x32_bf16(a,b,c,0,0,0);
}

// log2(10000)/32
#define ROPE_K 0.41524101186092030f
// 0.125 * log2(e)  (sm_scale folded with exp->exp2 conversion)
#define QS 0.18033688011112042f
#define NEGBIG -1.0e30f

// ============================================================
// cos/sin table, layout [n][i]: tab[(n<<5)+i] = {cos(n*invfreq_i),
// sin(n*invfreq_i)}, n in [0,1024), i in [0,32).  256 KB, 32K sincos.
// ============================================================
__global__ __launch_bounds__(256) void rope_table_kernel(float2* __restrict__ tab)
{
  int id = blockIdx.x*256 + threadIdx.x;   // 32768 total
  int n = id >> 5, i = id & 31;
  float inv = exp2f(-(float)i * ROPE_K);
  float sn, cs; sincosf((float)n * inv, &sn, &cs);
  tab[id] = make_float2(cs, sn);
}

// ============================================================
// Fused staging (conflict-free mappings verified R8: conflicts = 0).
// LDS layout bit-identical to verified R4-R8:
//   K elem = kb*1024 + half*512 + quad*128 + l15*8 + j
//   V elem = s*1024  + half*512 + qd*128  + l15v*8 + j
// R9 change: the kernel is lockstep-latency-bound (conflicts 0, all
// pipes <40%) -- so halve the sync count: kt-unroll x2 over FOUR LDS
// buffers, one barrier per two tiles, stage writes interleaved
// between the two compute clusters.  bf16 packing via cvt_pk.
// ============================================================
struct Stage {
  float4 ka0, ka1, c0, c1;
  float v[8];
};

__device__ __forceinline__ void stage_load(Stage& S,
    const float* __restrict__ xk, const float* __restrict__ xv,
    const float2* __restrict__ tab, int b, int h, int n, int sd0,
    int vrow0, int vlane)
{
  const float4* kg = (const float4*)(xk + ((((size_t)b*Nn + n)*Hh + h)<<6) + sd0);
  S.ka0 = kg[0]; S.ka1 = kg[1];
  const float4* tg = (const float4*)(tab + (n<<5) + (sd0>>1));  // 32B aligned
  S.c0 = tg[0]; S.c1 = tg[1];
  // V rows vrow0 + {0,1} + 16m, column vlane (each load wave-coalesced)
  const float* vb = xv + ((((size_t)b*Nn + vrow0)*Hh + h)<<6) + vlane;
  #pragma unroll
  for (int m=0;m<4;++m){
    S.v[2*m]   = vb[(16*m)*Hh*Dd];
    S.v[2*m+1] = vb[(16*m+1)*Hh*Dd];
  }
}

__device__ __forceinline__ void stage_write(const Stage& S,
    u16* __restrict__ Kl, u16* __restrict__ Vl, int kdest, int vdest)
{
  float kx[8]  = {S.ka0.x,S.ka0.y,S.ka0.z,S.ka0.w, S.ka1.x,S.ka1.y,S.ka1.z,S.ka1.w};
  float cs4[4] = {S.c0.x, S.c0.z, S.c1.x, S.c1.z};
  float sn4[4] = {S.c0.y, S.c0.w, S.c1.y, S.c1.w};
  uint32_t w[4];
  #pragma unroll
  for (int j=0;j<4;++j){
    float x0 = kx[2*j], x1 = kx[2*j+1];
    w[j] = packbf2(x0*cs4[j] - x1*sn4[j], x1*cs4[j] + x0*sn4[j]);
  }
  *(uint4*)&Kl[kdest] = make_uint4(w[0],w[1],w[2],w[3]);
  uint32_t wv[4];
  #pragma unroll
  for (int j=0;j<4;++j)
    wv[j] = packbf2(S.v[2*j], S.v[2*j+1]);
  *(uint4*)&Vl[vdest] = make_uint4(wv[0],wv[1],wv[2],wv[3]);
}

// ---- one tile of attention compute (verified R4-R8 core) ----
__device__ __forceinline__ void compute_tile(
    const u16* __restrict__ Kl, const u16* __restrict__ Vl,
    const float* __restrict__ biasS, int kt, int lane, int quad,
    const short8 (&qa)[2][2], short8 ones,
    f32x4 (&acc)[2][4], f32x4 (&l_acc)[2])
{
  uint32_t pk[4][2][2];           // [kb][h][mb]
  __builtin_amdgcn_s_setprio(1);
  #pragma unroll
  for (int kb=0;kb<4;++kb){
    short8 kf0 = *(const short8*)&Kl[(kb<<10) + (lane<<3)];
    short8 kf1 = *(const short8*)&Kl[(kb<<10) + 512 + (lane<<3)];
    f32x4 bias = *(const f32x4*)&biasS[(kt<<6)+(kb<<4)+(quad<<2)];
    #pragma unroll
    for (int mb=0;mb<2;++mb){
      f32x4 t = mfma16(kf0, qa[mb][0], bias);
      t = mfma16(kf1, qa[mb][1], t);
      // lane holds S^T[key=kb*16+quad*4+rr][q=mb*16+l15], log2-domain
      float p0 = __builtin_amdgcn_exp2f(t.x);
      float p1 = __builtin_amdgcn_exp2f(t.y);
      float p2 = __builtin_amdgcn_exp2f(t.z);
      float p3 = __builtin_amdgcn_exp2f(t.w);
      pk[kb][0][mb] = packbf2(p0,p1);
      pk[kb][1][mb] = packbf2(p2,p3);
    }
  }
  __builtin_amdgcn_s_setprio(0);

  short8 pa[2][2];
  #pragma unroll
  for (int mb=0;mb<2;++mb){
    U4S8 a0; a0.u = make_uint4(pk[0][0][mb], pk[1][0][mb], pk[2][0][mb], pk[3][0][mb]);
    U4S8 a1; a1.u = make_uint4(pk[0][1][mb], pk[1][1][mb], pk[2][1][mb], pk[3][1][mb]);
    pa[mb][0] = a0.s; pa[mb][1] = a1.s;
  }

  __builtin_amdgcn_s_setprio(1);
  #pragma unroll
  for (int mb=0;mb<2;++mb){
    l_acc[mb] = mfma16(pa[mb][0], ones, l_acc[mb]);
    l_acc[mb] = mfma16(pa[mb][1], ones, l_acc[mb]);
  }
  #pragma unroll
  for (int s=0;s<4;++s){
    short8 vb0 = *(const short8*)&Vl[(s<<10) + (lane<<3)];
    short8 vb1 = *(const short8*)&Vl[(s<<10) + 512 + (lane<<3)];
    #pragma unroll
    for (int mb=0;mb<2;++mb){
      acc[mb][s] = mfma16(pa[mb][0], vb0, acc[mb][s]);
      acc[mb][s] = mfma16(pa[mb][1], vb1, acc[mb][s]);
    }
  }
  __builtin_amdgcn_s_setprio(0);
}

// ============================================================
// Fused attention, R9: 2 tiles per barrier (4-buffer rotation).
// Grid 512 x 512thr (8 waves), 2 blocks/CU, 256 q rows per block.
// ============================================================
__global__ __launch_bounds__(512,4) void fused_attn_kernel(
    const float* __restrict__ xq, const float* __restrict__ xk,
    const float* __restrict__ xv, const int* __restrict__ vis,
    const float2* __restrict__ tab, float* __restrict__ out)
{
  __shared__ u16 KV[4][2][4096];    // [buf][K/V][frag-linear], 64 KiB
  __shared__ float biasS[Nn];       // key-bias 0 / -1e30, 4 KiB

  const int tid  = threadIdx.x;     // 0..511
  const int lane = tid & 63;
  const int wave = tid >> 6;        // 0..7
  const int l15  = lane & 15;
  const int quad = lane >> 4;

  // ---- XCD-aware decode (grid 512, 8 XCDs, 64 blocks/XCD) ----
  const int bid = blockIdx.x;
  const int xcd = bid & 7;
  const int ix  = bid >> 3;            // 0..63
  const int bh_ = (xcd<<4) | (ix>>2);  // 16 bh per XCD, 4 qt adjacent
  const int qt  = ix & 3;
  const int h   = bh_ & 7;
  const int b   = bh_ >> 3;
  const int qbase = qt<<8;             // 256 q rows per block

  const int* visb = vis + b*Nn;

  // ---- staging thread mappings (conflict-free, verified R8) ----
  const int srow = ((tid>>6)<<3) | (tid & 7);     // key row in tile
  const int sd0  = ((tid>>3) & 7) << 3;           // 8-d block
  const int kdest = ((srow>>4)<<10) + ((sd0>>5)<<9) + (((sd0>>3)&3)<<7) + ((srow&15)<<3);
  const int vgrp  = tid >> 6;          // 0..7
  const int vlane = tid & 63;          // d column
  const int vdest = ((vlane>>4)<<10) + ((vgrp&1)<<9) + (((vgrp>>1)&3)<<7) + ((vlane&15)<<3);

  // ---- stage vis -> f32 bias in LDS (once) ----
  {
    int2 vi = *(const int2*)&visb[tid<<1];
    float2 bs;
    bs.x = vi.x ? 0.f : NEGBIG;
    bs.y = vi.y ? 0.f : NEGBIG;
    *(float2*)&biasS[tid<<1] = bs;
  }

  // ---- roped Q B-frags in registers (QS folded), 2 m-blocks ----
  short8 qa[2][2];
  #pragma unroll
  for (int mb=0; mb<2; ++mb){
    int n = qbase + (wave<<5) + (mb<<4) + l15;
    const float* src = xq + ((((size_t)b*Nn + n)*Hh + h)<<6);
    #pragma unroll
    for (int half=0; half<2; ++half){
      int d0 = (half<<5) + (quad<<3);
      const float4* g = (const float4*)(src + d0);
      float4 u0 = g[0], u1 = g[1];
      float xx[8] = {u0.x,u0.y,u0.z,u0.w, u1.x,u1.y,u1.z,u1.w};
      uint32_t w[4];
      #pragma unroll
      for (int j=0;j<4;++j){
        int i2 = (d0>>1) + j;
        float2 t = tab[(n<<5)+i2];
        float x0 = xx[2*j], x1 = xx[2*j+1];
        w[j] = packbf2((x0*t.x - x1*t.y)*QS, (x1*t.x + x0*t.y)*QS);
      }
      U4S8 t2; t2.u = make_uint4(w[0],w[1],w[2],w[3]);
      qa[mb][half] = t2.s;
    }
  }

  U4S8 ones_u; ones_u.u = make_uint4(0x3F803F80u,0x3F803F80u,0x3F803F80u,0x3F803F80u);
  const short8 ones = ones_u.s;

  f32x4 acc[2][4];
  f32x4 l_acc[2];
  #pragma unroll
  for (int mb=0;mb<2;++mb){
    l_acc[mb] = (f32x4){0.f,0.f,0.f,0.f};
    #pragma unroll
    for (int s=0;s<4;++s) acc[mb][s] = (f32x4){0.f,0.f,0.f,0.f};
  }

  // ---- prologue: stage tiles 0,1; issue loads for tiles 2,3 ----
  Stage S0, S1;
  stage_load(S0, xk, xv, tab, b, h, srow, sd0, vgrp<<1, vlane);
  stage_write(S0, &KV[0][0][0], &KV[0][1][0], kdest, vdest);
  stage_load(S1, xk, xv, tab, b, h, 64 + srow, sd0, 64 + (vgrp<<1), vlane);
  stage_write(S1, &KV[1][0][0], &KV[1][1][0], kdest, vdest);
  stage_load(S0, xk, xv, tab, b, h, 128 + srow, sd0, 128 + (vgrp<<1), vlane);
  stage_load(S1, xk, xv, tab, b, h, 192 + srow, sd0, 192 + (vgrp<<1), vlane);
  __syncthreads();

  // ---- main loop: 2 tiles per barrier, 4-buffer rotation ----
  for (int t=0; t<8; ++t){
    const int k0 = 2*t, k1 = 2*t+1;

    compute_tile(&KV[k0&3][0][0], &KV[k0&3][1][0], biasS, k0,
                 lane, quad, qa, ones, acc, l_acc);
    if (t < 7)  // write tile k0+2 (its buffer was consumed last iter)
      stage_write(S0, &KV[(k0+2)&3][0][0], &KV[(k0+2)&3][1][0], kdest, vdest);

    compute_tile(&KV[k1&3][0][0], &KV[k1&3][1][0], biasS, k1,
                 lane, quad, qa, ones, acc, l_acc);
    if (t < 7)
      stage_write(S1, &KV[(k1+2)&3][0][0], &KV[(k1+2)&3][1][0], kdest, vdest);

    if (t < 6){ // issue loads for tiles k0+4, k1+4
      stage_load(S0, xk, xv, tab, b, h, ((k0+4)<<6) + srow, sd0,
                 ((k0+4)<<6) + (vgrp<<1), vlane);
      stage_load(S1, xk, xv, tab, b, h, ((k1+4)<<6) + srow, sd0,
                 ((k1+4)<<6) + (vgrp<<1), vlane);
    }
    __syncthreads();
  }

  // ---- epilogue: l already per-q in C layout; normalize + store ----
  #pragma unroll
  for (int mb=0;mb<2;++mb){
    #pragma unroll
    for (int rr=0;rr<4;++rr){
      int qrow = qbase + (wave<<5) + (mb<<4) + (quad<<2) + rr;
      float lq = l_acc[mb][rr];
      float invl = (biasS[qrow] == 0.f && lq > 0.f) ? 1.f/lq : 0.f;
      float* ob = out + ((((size_t)b*Nn + qrow)*Hh + h)<<6);
      #pragma unroll
      for (int s=0;s<4;++s)
        ob[(s<<4)+l15] = acc[mb][s][rr]*invl;
    }
  }
}

// ============================================================
// Fallback (inline sincos, no workspace) — used if ws too small
// ============================================================
__device__ __forceinline__ uint32_t f2bf(float f){
  union{float f;uint32_t i;} v; v.f=f;
  return (v.i + 0x7fffu + ((v.i>>16)&1u))>>16;
}

__device__ __forceinline__ void stage_rope_row_fb(const float* __restrict__ src,
                                                  u16 (*dst)[72],
                                                  int n_global, int sr, int d0)
{
  const float4* g = (const float4*)src;
  float4 a0 = g[0], a1 = g[1], a2 = g[2], a3 = g[3];
  float xx[16] = {a0.x,a0.y,a0.z,a0.w, a1.x,a1.y,a1.z,a1.w,
                  a2.x,a2.y,a2.z,a2.w, a3.x,a3.y,a3.z,a3.w};
  uint32_t w[8];
  #pragma unroll
  for (int j=0;j<8;++j){
    int i = (d0>>1)+j;
    float inv = exp2f(-(float)i * ROPE_K);
    float ang = (float)n_global * inv;
    float sn, cs; sincosf(ang, &sn, &cs);
    float x0 = xx[2*j], x1 = xx[2*j+1];
    float q0 = x0*cs - x1*sn;
    float q1 = x1*cs + x0*sn;
    w[j] = f2bf(q0) | (f2bf(q1)<<16);
  }
  *(uint4*)&dst[sr][d0]   = make_uint4(w[0],w[1],w[2],w[3]);
  *(uint4*)&dst[sr][d0+8] = make_uint4(w[4],w[5],w[6],w[7]);
}

__global__ __launch_bounds__(256,2) void attn_fallback(
    const float* __restrict__ xq, const float* __restrict__ xk,
    const float* __restrict__ xv, const int* __restrict__ vis,
    float* __restrict__ out)
{
  __shared__ u16 Qs[64][72];
  __shared__ u16 Ks[64][72];
  __shared__ u16 Vt[64][72];
  __shared__ u16 Ps[4][16][72];
  __shared__ float viss[64];

  const int tid  = threadIdx.x;
  const int wave = tid >> 6;
  const int lane = tid & 63;
  const int l15  = lane & 15;
  const int quad = lane >> 4;

  const int bid = blockIdx.x;
  const int qt = bid & 15;
  const int h  = (bid >> 4) & 7;
  const int b  = bid >> 7;

  const int sr = tid >> 2;
  const int d0 = (tid & 3) << 4;

  {
    int ng = (qt<<6) + sr;
    const float* src = xq + ((((size_t)b*Nn + ng)*Hh + h)<<6) + d0;
    stage_rope_row_fb(src, Qs, ng, sr, d0);
  }
  __syncthreads();

  short8 qa0 = *(const short8*)&Qs[(wave<<4)+l15][quad<<3];
  short8 qa1 = *(const short8*)&Qs[(wave<<4)+l15][(quad<<3)+32];

  f32x4 acc[4];
  #pragma unroll
  for (int s=0;s<4;++s) acc[s] = (f32x4){0.f,0.f,0.f,0.f};
  float m_r[4], l_r[4];
  #pragma unroll
  for (int rr=0;rr<4;++rr){ m_r[rr] = -1e30f; l_r[rr] = 0.f; }

  for (int kt=0; kt<16; ++kt){
    __syncthreads();
    {
      int ng = (kt<<6) + sr;
      const float* src = xk + ((((size_t)b*Nn + ng)*Hh + h)<<6) + d0;
      stage_rope_row_fb(src, Ks, ng, sr, d0);
    }
    {
      int ng = (kt<<6) + sr;
      const float4* g = (const float4*)(xv + ((((size_t)b*Nn + ng)*Hh + h)<<6) + d0);
      float4 a0 = g[0], a1 = g[1], a2 = g[2], a3 = g[3];
      float vv16[16] = {a0.x,a0.y,a0.z,a0.w, a1.x,a1.y,a1.z,a1.w,
                        a2.x,a2.y,a2.z,a2.w, a3.x,a3.y,a3.z,a3.w};
      #pragma unroll
      for (int j=0;j<16;++j) Vt[d0+j][sr] = (u16)f2bf(vv16[j]);
    }
    if (tid < 64) viss[tid] = (vis[b*Nn + (kt<<6) + tid] != 0) ? 1.f : 0.f;
    __syncthreads();

    f32x4 s4[4];
    #pragma unroll
    for (int n=0;n<4;++n){
      short8 kb0 = *(const short8*)&Ks[(n<<4)+l15][quad<<3];
      short8 kb1 = *(const short8*)&Ks[(n<<4)+l15][(quad<<3)+32];
      f32x4 t = (f32x4){0.f,0.f,0.f,0.f};
      t = mfma16(qa0, kb0, t);
      t = mfma16(qa1, kb1, t);
      s4[n] = t;
    }
    float vv[4];
    #pragma unroll
    for (int n=0;n<4;++n) vv[n] = viss[(n<<4)+l15];

    float p[4][4];
    #pragma unroll
    for (int rr=0; rr<4; ++rr){
      float sc[4];
      #pragma unroll
      for (int n=0;n<4;++n) sc[n] = (vv[n] > 0.f) ? s4[n][rr]*0.125f : -1e30f;
      float tm = fmaxf(fmaxf(sc[0],sc[1]), fmaxf(sc[2],sc[3]));
      tm = fmaxf(tm, __shfl_xor(tm,1));
      tm = fmaxf(tm, __shfl_xor(tm,2));
      tm = fmaxf(tm, __shfl_xor(tm,4));
      tm = fmaxf(tm, __shfl_xor(tm,8));
      float mnew  = fmaxf(m_r[rr], tm);
      float alpha = __expf(m_r[rr] - mnew);
      m_r[rr] = mnew;
      float psum = 0.f;
      #pragma unroll
      for (int n=0;n<4;++n){
        float pv = (vv[n] > 0.f) ? __expf(sc[n] - mnew) : 0.f;
        p[n][rr] = pv; psum += pv;
      }
      l_r[rr] = l_r[rr]*alpha + psum;
      #pragma unroll
      for (int s=0;s<4;++s) acc[s][rr] *= alpha;
    }

    #pragma unroll
    for (int n=0;n<4;++n)
      #pragma unroll
      for (int rr=0;rr<4;++rr)
        Ps[wave][(quad<<2)+rr][(n<<4)+l15] = (u16)f2bf(p[n][rr]);
    asm volatile("s_waitcnt lgkmcnt(0)" ::: "memory");
    short8 pa0 = *(const short8*)&Ps[wave][l15][quad<<3];
    short8 pa1 = *(const short8*)&Ps[wave][l15][(quad<<3)+32];

    #pragma unroll
    for (int s=0;s<4;++s){
      short8 vb0 = *(const short8*)&Vt[(s<<4)+l15][quad<<3];
      short8 vb1 = *(const short8*)&Vt[(s<<4)+l15][(quad<<3)+32];
      acc[s] = mfma16(pa0, vb0, acc[s]);
      acc[s] = mfma16(pa1, vb1, acc[s]);
    }
  }

  #pragma unroll
  for (int rr=0;rr<4;++rr){
    float t = l_r[rr];
    t += __shfl_xor(t,1); t += __shfl_xor(t,2);
    t += __shfl_xor(t,4); t += __shfl_xor(t,8);
    int row = (qt<<6) + (wave<<4) + (quad<<2) + rr;
    int qv  = vis[b*Nn + row];
    float invl = (qv != 0 && t > 0.f) ? 1.f/t : 0.f;
    size_t obase = (((size_t)b*Nn + row)*Hh + h) << 6;
    #pragma unroll
    for (int s=0;s<4;++s)
      out[obase + (s<<4) + l15] = acc[s][rr]*invl;
  }
}

extern "C" void kernel_launch(void* const* d_in, const int* in_sizes, int n_in,
                              void* d_out, int out_size, void* d_ws, size_t ws_size,
                              hipStream_t stream)
{
  const float* xq = (const float*)d_in[0];
  const float* xk = (const float*)d_in[1];
  const float* xv = (const float*)d_in[2];
  const int* vis  = (const int*)d_in[3];
  float* out = (float*)d_out;

  const size_t tab_bytes = (size_t)32*1024*sizeof(float2);   // 256 KB

  if (d_ws != nullptr && ws_size >= tab_bytes){
    float2* tab = (float2*)d_ws;
    rope_table_kernel<<<dim3(128), dim3(256), 0, stream>>>(tab);
    fused_attn_kernel<<<dim3(Bb*Hh*4), dim3(512), 0, stream>>>(xq, xk, xv, vis, tab, out);
  } else {
    attn_fallback<<<dim3(Bb*Hh*(Nn/64)), dim3(256), 0, stream>>>(xq, xk, xv, vis, out);
  }
}

// Round 12
// 179.821 us; speedup vs baseline: 1.6319x; 1.6319x over previous
//
#include <hip/hip_runtime.h>
#include <hip/hip_bf16.h>
#include <stdint.h>

#define Bb 16
#define Nn 1024
#define Hh 8
#define Dd 64

typedef unsigned short u16;
typedef float f32x4 __attribute__((ext_vector_type(4)));
typedef short short8 __attribute__((ext_vector_type(8)));

union U4S8 { uint4 u; short8 s; };
union BF2U { __hip_bfloat162 h; uint32_t u; };

__device__ __forceinline__ uint32_t f2bf(float f){
  union{float f;uint32_t i;} v; v.f=f;
  return (v.i + 0x7fffu + ((v.i>>16)&1u))>>16;
}

__device__ __forceinline__ f32x4 mfma16(short8 a, short8 b, f32x4 c){
  return __builtin_amdgcn_mfma_f32_16x16x32_bf16(a,b,c,0,0,0);
}

// log2(10000)/32
#define ROPE_K 0.41524101186092030f
// 0.125 * log2(e)  (sm_scale folded with exp->exp2 conversion)
#define QS 0.18033688011112042f
#define NEGBIG -1.0e30f

// ============================================================
// cos/sin table, layout [n][i]: tab[(n<<5)+i] = {cos(n*invfreq_i),
// sin(n*invfreq_i)}, n in [0,1024), i in [0,32).  256 KB, 32K sincos.
// ============================================================
__global__ __launch_bounds__(256) void rope_table_kernel(float2* __restrict__ tab)
{
  int id = blockIdx.x*256 + threadIdx.x;   // 32768 total
  int n = id >> 5, i = id & 31;
  float inv = exp2f(-(float)i * ROPE_K);
  float sn, cs; sincosf((float)n * inv, &sn, &cs);
  tab[id] = make_float2(cs, sn);
}

// ============================================================
// R12 = REVERT to best-measured composition after R9/R11's spill
// disaster (2 live Stage structs + 4-buffer rotation -> scratch:
// WRITE_SIZE 223MB, 195-280us).  This is R6's schedule (ONE Stage,
// load kt+1 at top of iter, write after PV, 2 LDS buffers, 1 barrier
// per kt -- measured 80.2us) + R8's conflict-free K thread mapping
// (srow=(wave<<3)|(tid&7), sd0=((tid>>3)&7)<<3 -> bank-start
// 4*(tid&7); measured conflicts = 0).  kt+2 prefetch dropped
// (isolated cost ~+3.4us in R8).
// LDS layout bit-identical to verified R4-R8:
//   K elem = kb*1024 + half*512 + quad*128 + l15*8 + j
//   V elem = s*1024  + half*512 + qd*128  + l15v*8 + j
// ============================================================
struct Stage {
  float4 ka0, ka1, c0, c1;
  float v[8];
};

__device__ __forceinline__ void stage_load(Stage& S,
    const float* __restrict__ xk, const float* __restrict__ xv,
    const float2* __restrict__ tab, int b, int h, int n, int sd0,
    int vrow0, int vlane)
{
  const float4* kg = (const float4*)(xk + ((((size_t)b*Nn + n)*Hh + h)<<6) + sd0);
  S.ka0 = kg[0]; S.ka1 = kg[1];
  const float4* tg = (const float4*)(tab + (n<<5) + (sd0>>1));  // 32B aligned
  S.c0 = tg[0]; S.c1 = tg[1];
  // V rows vrow0 + {0,1} + 16m, column vlane (each load wave-coalesced)
  const float* vb = xv + ((((size_t)b*Nn + vrow0)*Hh + h)<<6) + vlane;
  #pragma unroll
  for (int m=0;m<4;++m){
    S.v[2*m]   = vb[(16*m)*Hh*Dd];
    S.v[2*m+1] = vb[(16*m+1)*Hh*Dd];
  }
}

__device__ __forceinline__ void stage_write(const Stage& S,
    u16* __restrict__ Kl, u16* __restrict__ Vl, int kdest, int vdest)
{
  float kx[8]  = {S.ka0.x,S.ka0.y,S.ka0.z,S.ka0.w, S.ka1.x,S.ka1.y,S.ka1.z,S.ka1.w};
  float cs4[4] = {S.c0.x, S.c0.z, S.c1.x, S.c1.z};
  float sn4[4] = {S.c0.y, S.c0.w, S.c1.y, S.c1.w};
  uint32_t w[4];
  #pragma unroll
  for (int j=0;j<4;++j){
    float x0 = kx[2*j], x1 = kx[2*j+1];
    float q0 = x0*cs4[j] - x1*sn4[j];
    float q1 = x1*cs4[j] + x0*sn4[j];
    w[j] = f2bf(q0) | (f2bf(q1)<<16);
  }
  *(uint4*)&Kl[kdest] = make_uint4(w[0],w[1],w[2],w[3]);
  uint32_t wv[4];
  #pragma unroll
  for (int j=0;j<4;++j)
    wv[j] = f2bf(S.v[2*j]) | (f2bf(S.v[2*j+1])<<16);
  *(uint4*)&Vl[vdest] = make_uint4(wv[0],wv[1],wv[2],wv[3]);
}

// ============================================================
// Fused attention.  Grid 512 x 512thr (8 waves), 2 blocks/CU, 256 q
// rows per block (per-wave compute identical to verified R4: mb=2).
// Each block ropes K / permutes V from raw f32 into LDS itself; the
// 4 blocks per (b,h) share an XCD so redundant f32 reads are L2 hits.
// T14 split staging: loads at top of iter kt, writes after PV.
// ============================================================
__global__ __launch_bounds__(512,4) void fused_attn_kernel(
    const float* __restrict__ xq, const float* __restrict__ xk,
    const float* __restrict__ xv, const int* __restrict__ vis,
    const float2* __restrict__ tab, float* __restrict__ out)
{
  __shared__ u16 KV[2][2][4096];    // [buf][K/V][frag-linear], 32 KiB
  __shared__ float biasS[Nn];       // key-bias 0 / -1e30, 4 KiB

  const int tid  = threadIdx.x;     // 0..511
  const int lane = tid & 63;
  const int wave = tid >> 6;        // 0..7
  const int l15  = lane & 15;
  const int quad = lane >> 4;

  // ---- XCD-aware decode (grid 512, 8 XCDs, 64 blocks/XCD) ----
  const int bid = blockIdx.x;
  const int xcd = bid & 7;
  const int ix  = bid >> 3;            // 0..63
  const int bh_ = (xcd<<4) | (ix>>2);  // 16 bh per XCD, 4 qt adjacent
  const int qt  = ix & 3;
  const int h   = bh_ & 7;
  const int b   = bh_ >> 3;
  const int qbase = qt<<8;             // 256 q rows per block

  const int* visb = vis + b*Nn;

  // ---- staging thread mappings (both conflict-free, verified R8) ----
  const int srow = ((tid>>6)<<3) | (tid & 7);     // key row in tile
  const int sd0  = ((tid>>3) & 7) << 3;           // 8-d block
  const int kdest = ((srow>>4)<<10) + ((sd0>>5)<<9) + (((sd0>>3)&3)<<7) + ((srow&15)<<3);
  const int vgrp  = tid >> 6;          // 0..7
  const int vlane = tid & 63;          // d column
  const int vdest = ((vlane>>4)<<10) + ((vgrp&1)<<9) + (((vgrp>>1)&3)<<7) + ((vlane&15)<<3);

  // ---- stage vis -> f32 bias in LDS (once) ----
  {
    int2 vi = *(const int2*)&visb[tid<<1];
    float2 bs;
    bs.x = vi.x ? 0.f : NEGBIG;
    bs.y = vi.y ? 0.f : NEGBIG;
    *(float2*)&biasS[tid<<1] = bs;
  }

  // ---- roped Q B-frags in registers (QS folded), 2 m-blocks ----
  short8 qa[2][2];
  #pragma unroll
  for (int mb=0; mb<2; ++mb){
    int n = qbase + (wave<<5) + (mb<<4) + l15;
    const float* src = xq + ((((size_t)b*Nn + n)*Hh + h)<<6);
    #pragma unroll
    for (int half=0; half<2; ++half){
      int d0 = (half<<5) + (quad<<3);
      const float4* g = (const float4*)(src + d0);
      float4 u0 = g[0], u1 = g[1];
      float xx[8] = {u0.x,u0.y,u0.z,u0.w, u1.x,u1.y,u1.z,u1.w};
      uint32_t w[4];
      #pragma unroll
      for (int j=0;j<4;++j){
        int i2 = (d0>>1) + j;
        float2 t = tab[(n<<5)+i2];
        float x0 = xx[2*j], x1 = xx[2*j+1];
        float q0 = (x0*t.x - x1*t.y)*QS;
        float q1 = (x1*t.x + x0*t.y)*QS;
        w[j] = f2bf(q0) | (f2bf(q1)<<16);
      }
      U4S8 t2; t2.u = make_uint4(w[0],w[1],w[2],w[3]);
      qa[mb][half] = t2.s;
    }
  }

  U4S8 ones_u; ones_u.u = make_uint4(0x3F803F80u,0x3F803F80u,0x3F803F80u,0x3F803F80u);
  const short8 ones = ones_u.s;

  f32x4 acc[2][4];
  f32x4 l_acc[2];
  #pragma unroll
  for (int mb=0;mb<2;++mb){
    l_acc[mb] = (f32x4){0.f,0.f,0.f,0.f};
    #pragma unroll
    for (int s=0;s<4;++s) acc[mb][s] = (f32x4){0.f,0.f,0.f,0.f};
  }

  // ---- stage tile 0 into buf 0 ----
  {
    Stage S;
    stage_load(S, xk, xv, tab, b, h, srow, sd0, vgrp<<1, vlane);
    stage_write(S, &KV[0][0][0], &KV[0][1][0], kdest, vdest);
  }
  __syncthreads();

  for (int kt=0; kt<16; ++kt){
    const int cur = kt & 1;

    // ---- issue loads for kt+1 early (latency hides under compute) ----
    Stage S;
    if (kt < 15)
      stage_load(S, xk, xv, tab, b, h, ((kt+1)<<6) + srow, sd0,
                 ((kt+1)<<6) + (vgrp<<1), vlane);

    // ---- S^T = K Q^T per kb (bias C-init = mask), exp2+pack in-register ----
    uint32_t pk[4][2][2];           // [kb][h][mb]
    __builtin_amdgcn_s_setprio(1);
    #pragma unroll
    for (int kb=0;kb<4;++kb){
      short8 kf0 = *(const short8*)&KV[cur][0][(kb<<10) + (lane<<3)];
      short8 kf1 = *(const short8*)&KV[cur][0][(kb<<10) + 512 + (lane<<3)];
      f32x4 bias = *(const f32x4*)&biasS[(kt<<6)+(kb<<4)+(quad<<2)];
      #pragma unroll
      for (int mb=0;mb<2;++mb){
        f32x4 t = mfma16(kf0, qa[mb][0], bias);
        t = mfma16(kf1, qa[mb][1], t);
        // lane holds S^T[key=kb*16+quad*4+rr][q=mb*16+l15], log2-domain
        float p0 = __builtin_amdgcn_exp2f(t.x);
        float p1 = __builtin_amdgcn_exp2f(t.y);
        float p2 = __builtin_amdgcn_exp2f(t.z);
        float p3 = __builtin_amdgcn_exp2f(t.w);
        BF2U e0; e0.h = __float22bfloat162_rn(make_float2(p0,p1));
        BF2U e1; e1.h = __float22bfloat162_rn(make_float2(p2,p3));
        pk[kb][0][mb] = e0.u;
        pk[kb][1][mb] = e1.u;
      }
    }
    __builtin_amdgcn_s_setprio(0);

    // ---- assemble P A-frags (pure register repack) ----
    short8 pa[2][2];
    #pragma unroll
    for (int mb=0;mb<2;++mb){
      U4S8 a0; a0.u = make_uint4(pk[0][0][mb], pk[1][0][mb], pk[2][0][mb], pk[3][0][mb]);
      U4S8 a1; a1.u = make_uint4(pk[0][1][mb], pk[1][1][mb], pk[2][1][mb], pk[3][1][mb]);
      pa[mb][0] = a0.s; pa[mb][1] = a1.s;
    }

    // ---- l += P * ones (matrix pipe), O += P V ----
    __builtin_amdgcn_s_setprio(1);
    #pragma unroll
    for (int mb=0;mb<2;++mb){
      l_acc[mb] = mfma16(pa[mb][0], ones, l_acc[mb]);
      l_acc[mb] = mfma16(pa[mb][1], ones, l_acc[mb]);
    }
    #pragma unroll
    for (int s=0;s<4;++s){
      short8 vb0 = *(const short8*)&KV[cur][1][(s<<10) + (lane<<3)];
      short8 vb1 = *(const short8*)&KV[cur][1][(s<<10) + 512 + (lane<<3)];
      #pragma unroll
      for (int mb=0;mb<2;++mb){
        acc[mb][s] = mfma16(pa[mb][0], vb0, acc[mb][s]);
        acc[mb][s] = mfma16(pa[mb][1], vb1, acc[mb][s]);
      }
    }
    __builtin_amdgcn_s_setprio(0);

    // ---- finish staging kt+1 into the other buffer ----
    if (kt < 15)
      stage_write(S, &KV[cur^1][0][0], &KV[cur^1][1][0], kdest, vdest);

    __syncthreads();
  }

  // ---- epilogue: l already per-q in C layout; normalize + store ----
  #pragma unroll
  for (int mb=0;mb<2;++mb){
    #pragma unroll
    for (int rr=0;rr<4;++rr){
      int qrow = qbase + (wave<<5) + (mb<<4) + (quad<<2) + rr;
      float lq = l_acc[mb][rr];
      float invl = (biasS[qrow] == 0.f && lq > 0.f) ? 1.f/lq : 0.f;
      float* ob = out + ((((size_t)b*Nn + qrow)*Hh + h)<<6);
      #pragma unroll
      for (int s=0;s<4;++s)
        ob[(s<<4)+l15] = acc[mb][s][rr]*invl;
    }
  }
}

// ============================================================
// Fallback (inline sincos, no workspace) — used if ws too small
// ============================================================
__device__ __forceinline__ void stage_rope_row_fb(const float* __restrict__ src,
                                                  u16 (*dst)[72],
                                                  int n_global, int sr, int d0)
{
  const float4* g = (const float4*)src;
  float4 a0 = g[0], a1 = g[1], a2 = g[2], a3 = g[3];
  float xx[16] = {a0.x,a0.y,a0.z,a0.w, a1.x,a1.y,a1.z,a1.w,
                  a2.x,a2.y,a2.z,a2.w, a3.x,a3.y,a3.z,a3.w};
  uint32_t w[8];
  #pragma unroll
  for (int j=0;j<8;++j){
    int i = (d0>>1)+j;
    float inv = exp2f(-(float)i * ROPE_K);
    float ang = (float)n_global * inv;
    float sn, cs; sincosf(ang, &sn, &cs);
    float x0 = xx[2*j], x1 = xx[2*j+1];
    float q0 = x0*cs - x1*sn;
    float q1 = x1*cs + x0*sn;
    w[j] = f2bf(q0) | (f2bf(q1)<<16);
  }
  *(uint4*)&dst[sr][d0]   = make_uint4(w[0],w[1],w[2],w[3]);
  *(uint4*)&dst[sr][d0+8] = make_uint4(w[4],w[5],w[6],w[7]);
}

__global__ __launch_bounds__(256,2) void attn_fallback(
    const float* __restrict__ xq, const float* __restrict__ xk,
    const float* __restrict__ xv, const int* __restrict__ vis,
    float* __restrict__ out)
{
  __shared__ u16 Qs[64][72];
  __shared__ u16 Ks[64][72];
  __shared__ u16 Vt[64][72];
  __shared__ u16 Ps[4][16][72];
  __shared__ float viss[64];

  const int tid  = threadIdx.x;
  const int wave = tid >> 6;
  const int lane = tid & 63;
  const int l15  = lane & 15;
  const int quad = lane >> 4;

  const int bid = blockIdx.x;
  const int qt = bid & 15;
  const int h  = (bid >> 4) & 7;
  const int b  = bid >> 7;

  const int sr = tid >> 2;
  const int d0 = (tid & 3) << 4;

  {
    int ng = (qt<<6) + sr;
    const float* src = xq + ((((size_t)b*Nn + ng)*Hh + h)<<6) + d0;
    stage_rope_row_fb(src, Qs, ng, sr, d0);
  }
  __syncthreads();

  short8 qa0 = *(const short8*)&Qs[(wave<<4)+l15][quad<<3];
  short8 qa1 = *(const short8*)&Qs[(wave<<4)+l15][(quad<<3)+32];

  f32x4 acc[4];
  #pragma unroll
  for (int s=0;s<4;++s) acc[s] = (f32x4){0.f,0.f,0.f,0.f};
  float m_r[4], l_r[4];
  #pragma unroll
  for (int rr=0;rr<4;++rr){ m_r[rr] = -1e30f; l_r[rr] = 0.f; }

  for (int kt=0; kt<16; ++kt){
    __syncthreads();
    {
      int ng = (kt<<6) + sr;
      const float* src = xk + ((((size_t)b*Nn + ng)*Hh + h)<<6) + d0;
      stage_rope_row_fb(src, Ks, ng, sr, d0);
    }
    {
      int ng = (kt<<6) + sr;
      const float4* g = (const float4*)(xv + ((((size_t)b*Nn + ng)*Hh + h)<<6) + d0);
      float4 a0 = g[0], a1 = g[1], a2 = g[2], a3 = g[3];
      float vv16[16] = {a0.x,a0.y,a0.z,a0.w, a1.x,a1.y,a1.z,a1.w,
                        a2.x,a2.y,a2.z,a2.w, a3.x,a3.y,a3.z,a3.w};
      #pragma unroll
      for (int j=0;j<16;++j) Vt[d0+j][sr] = (u16)f2bf(vv16[j]);
    }
    if (tid < 64) viss[tid] = (vis[b*Nn + (kt<<6) + tid] != 0) ? 1.f : 0.f;
    __syncthreads();

    f32x4 s4[4];
    #pragma unroll
    for (int n=0;n<4;++n){
      short8 kb0 = *(const short8*)&Ks[(n<<4)+l15][quad<<3];
      short8 kb1 = *(const short8*)&Ks[(n<<4)+l15][(quad<<3)+32];
      f32x4 t = (f32x4){0.f,0.f,0.f,0.f};
      t = mfma16(qa0, kb0, t);
      t = mfma16(qa1, kb1, t);
      s4[n] = t;
    }
    float vv[4];
    #pragma unroll
    for (int n=0;n<4;++n) vv[n] = viss[(n<<4)+l15];

    float p[4][4];
    #pragma unroll
    for (int rr=0; rr<4; ++rr){
      float sc[4];
      #pragma unroll
      for (int n=0;n<4;++n) sc[n] = (vv[n] > 0.f) ? s4[n][rr]*0.125f : -1e30f;
      float tm = fmaxf(fmaxf(sc[0],sc[1]), fmaxf(sc[2],sc[3]));
      tm = fmaxf(tm, __shfl_xor(tm,1));
      tm = fmaxf(tm, __shfl_xor(tm,2));
      tm = fmaxf(tm, __shfl_xor(tm,4));
      tm = fmaxf(tm, __shfl_xor(tm,8));
      float mnew  = fmaxf(m_r[rr], tm);
      float alpha = __expf(m_r[rr] - mnew);
      m_r[rr] = mnew;
      float psum = 0.f;
      #pragma unroll
      for (int n=0;n<4;++n){
        float pv = (vv[n] > 0.f) ? __expf(sc[n] - mnew) : 0.f;
        p[n][rr] = pv; psum += pv;
      }
      l_r[rr] = l_r[rr]*alpha + psum;
      #pragma unroll
      for (int s=0;s<4;++s) acc[s][rr] *= alpha;
    }

    #pragma unroll
    for (int n=0;n<4;++n)
      #pragma unroll
      for (int rr=0;rr<4;++rr)
        Ps[wave][(quad<<2)+rr][(n<<4)+l15] = (u16)f2bf(p[n][rr]);
    asm volatile("s_waitcnt lgkmcnt(0)" ::: "memory");
    short8 pa0 = *(const short8*)&Ps[wave][l15][quad<<3];
    short8 pa1 = *(const short8*)&Ps[wave][l15][(quad<<3)+32];

    #pragma unroll
    for (int s=0;s<4;++s){
      short8 vb0 = *(const short8*)&Vt[(s<<4)+l15][quad<<3];
      short8 vb1 = *(const short8*)&Vt[(s<<4)+l15][(quad<<3)+32];
      acc[s] = mfma16(pa0, vb0, acc[s]);
      acc[s] = mfma16(pa1, vb1, acc[s]);
    }
  }

  #pragma unroll
  for (int rr=0;rr<4;++rr){
    float t = l_r[rr];
    t += __shfl_xor(t,1); t += __shfl_xor(t,2);
    t += __shfl_xor(t,4); t += __shfl_xor(t,8);
    int row = (qt<<6) + (wave<<4) + (quad<<2) + rr;
    int qv  = vis[b*Nn + row];
    float invl = (qv != 0 && t > 0.f) ? 1.f/t : 0.f;
    size_t obase = (((size_t)b*Nn + row)*Hh + h) << 6;
    #pragma unroll
    for (int s=0;s<4;++s)
      out[obase + (s<<4) + l15] = acc[s][rr]*invl;
  }
}

extern "C" void kernel_launch(void* const* d_in, const int* in_sizes, int n_in,
                              void* d_out, int out_size, void* d_ws, size_t ws_size,
                              hipStream_t stream)
{
  const float* xq = (const float*)d_in[0];
  const float* xk = (const float*)d_in[1];
  const float* xv = (const float*)d_in[2];
  const int* vis  = (const int*)d_in[3];
  float* out = (float*)d_out;

  const size_t tab_bytes = (size_t)32*1024*sizeof(float2);   // 256 KB

  if (d_ws != nullptr && ws_size >= tab_bytes){
    float2* tab = (float2*)d_ws;
    rope_table_kernel<<<dim3(128), dim3(256), 0, stream>>>(tab);
    fused_attn_kernel<<<dim3(Bb*Hh*4), dim3(512), 0, stream>>>(xq, xk, xv, vis, tab, out);
  } else {
    attn_fallback<<<dim3(Bb*Hh*(Nn/64)), dim3(256), 0, stream>>>(xq, xk, xv, vis, out);
  }
}

// Round 13
// 176.022 us; speedup vs baseline: 1.6672x; 1.0216x over previous
//
#include <hip/hip_runtime.h>
#include <hip/hip_bf16.h>
#include <stdint.h>

#define Bb 16
#define Nn 1024
#define Hh 8
#define Dd 64

typedef unsigned short u16;
typedef float f32x4 __attribute__((ext_vector_type(4)));
typedef short short8 __attribute__((ext_vector_type(8)));

union U4S8 { uint4 u; short8 s; };
union BF2U { __hip_bfloat162 h; uint32_t u; };

__device__ __forceinline__ uint32_t f2bf(float f){
  union{float f;uint32_t i;} v; v.f=f;
  return (v.i + 0x7fffu + ((v.i>>16)&1u))>>16;
}

__device__ __forceinline__ f32x4 mfma16(short8 a, short8 b, f32x4 c){
  return __builtin_amdgcn_mfma_f32_16x16x32_bf16(a,b,c,0,0,0);
}

// async global->LDS, 16B per lane; LDS dst must be wave-uniform base + lane*16
typedef __attribute__((address_space(3))) uint32_t lds_u32;
typedef const __attribute__((address_space(1))) uint32_t glb_u32;
__device__ __forceinline__ void gl_lds16(const u16* g, u16* l){
  __builtin_amdgcn_global_load_lds((glb_u32*)g, (lds_u32*)l, 16, 0, 0);
}

// log2(10000)/32
#define ROPE_K 0.41524101186092030f
// 0.125 * log2(e)  (sm_scale folded with exp->exp2 conversion)
#define QS 0.18033688011112042f
#define NEGBIG -1.0e30f

// ============================================================
// R13 = restore of the best-measured configuration (R4, 176.0us
// total: prepass ~25 + attn8 56 + table 3 + fixed ~92 residual).
// The fused single-kernel architecture (R5-R12) measured 179.8 at
// best: it trades the prepass HBM round-trip for in-loop staging
// VALU at 2 blocks/CU, a net loss of ~3 us.  All fused structural
// levers are now measured (conflict fixes: hidden/neutral; deeper
// prefetch: +3us; multi-tile barriers: spill disaster).
// ============================================================

// cos/sin table, layout [n][i]: tab[(n<<5)+i] = {cos,sin}, 256 KB.
__global__ __launch_bounds__(256) void rope_table_kernel(float2* __restrict__ tab)
{
  int id = blockIdx.x*256 + threadIdx.x;   // 32768 total
  int n = id >> 5, i = id & 31;
  float inv = exp2f(-(float)i * ROPE_K);
  float sn, cs; sincosf((float)n * inv, &sn, &cs);
  tab[id] = make_float2(cs, sn);
}

// ============================================================
// Prepass -> fragment-linear layouts (per (bh,kt) block of 4096 u16):
//   Kf elem = kb*1024 + half*512 + quad*128 + l15*8 + j
//   Vf elem = s*1024 + half*512 + qd*128 + l15v*8 + j
//     slot(k) = (k&1) | ((k>>4)&3)<<1 | ((k>>2)&3)<<3 | ((k>>1)&1)<<5
// Fragment scatter lands in LDS; 16KB tile written out as fully-
// coalesced uint4s (measured: part of the 176.0 configuration).
// ============================================================
template<int USE_TAB>
__global__ __launch_bounds__(256) void prepass_kernel(
    const float* __restrict__ xk, const float* __restrict__ xv,
    u16* __restrict__ Kf, u16* __restrict__ Vf,
    const float2* __restrict__ tab)
{
  __shared__ u16 Kt[4096];
  __shared__ u16 Vt[4096];

  const int tid = threadIdx.x;
  const int bid = blockIdx.x;
  const int nt = bid & 15, h = (bid>>4)&7, b = bid>>7;
  const size_t bh = (size_t)b*Hh + h;
  const size_t tile = (bh<<4) + nt;            // (bh*16 + kt) blocks of 4096

  // ---- K rope -> fragment-linear (LDS) ----
  {
    int r = tid>>2, c = (tid&3)<<4;
    int n = (nt<<6) + r;
    const float4* g = (const float4*)(xk + ((((size_t)b*Nn + n)*Hh + h)<<6) + c);
    float4 a0=g[0],a1=g[1],a2=g[2],a3=g[3];
    float xx[16] = {a0.x,a0.y,a0.z,a0.w, a1.x,a1.y,a1.z,a1.w,
                    a2.x,a2.y,a2.z,a2.w, a3.x,a3.y,a3.z,a3.w};
    uint32_t w[8];
    #pragma unroll
    for (int j=0;j<8;++j){
      int ii = (c>>1)+j;
      float cs, sn;
      if (USE_TAB){
        float2 t = tab[(n<<5)+ii]; cs = t.x; sn = t.y;
      } else {
        float inv = exp2f(-(float)ii * ROPE_K);
        sincosf((float)n * inv, &sn, &cs);
      }
      float x0 = xx[2*j], x1 = xx[2*j+1];
      float q0 = x0*cs - x1*sn;
      float q1 = x1*cs + x0*sn;
      w[j] = f2bf(q0) | (f2bf(q1)<<16);
    }
    int kb = r>>4, l15 = r&15;
    int half = c>>5, qd = (c>>3)&3;
    int dest0 = (kb<<10) + (half<<9) + (qd<<7) + (l15<<3);
    *(uint4*)&Kt[dest0]       = make_uint4(w[0],w[1],w[2],w[3]);
    *(uint4*)&Kt[dest0 + 128] = make_uint4(w[4],w[5],w[6],w[7]);
  }

  // ---- V transpose + key permute -> fragment-linear (LDS) ----
  {
    int k = tid&63, ds = (tid>>6)<<4;
    int n = (nt<<6) + k;
    int slot = (k&1) | (((k>>4)&3)<<1) | (((k>>2)&3)<<3) | (((k>>1)&1)<<5);
    int half = slot>>5, qd = (slot>>3)&3, j = slot&7;
    const float4* g = (const float4*)(xv + ((((size_t)b*Nn + n)*Hh + h)<<6) + ds);
    float4 a0=g[0],a1=g[1],a2=g[2],a3=g[3];
    float vv[16] = {a0.x,a0.y,a0.z,a0.w, a1.x,a1.y,a1.z,a1.w,
                    a2.x,a2.y,a2.z,a2.w, a3.x,a3.y,a3.z,a3.w};
    #pragma unroll
    for (int jj=0;jj<16;++jj){
      int d = ds + jj;
      int s = d>>4, l15v = d&15;
      Vt[(s<<10) + (half<<9) + (qd<<7) + (l15v<<3) + j] = (u16)f2bf(vv[jj]);
    }
  }

  __syncthreads();

  // ---- coalesced writeout: 16KB as linear uint4 ----
  {
    const uint4* ks = (const uint4*)Kt;
    const uint4* vs = (const uint4*)Vt;
    uint4* kd = (uint4*)(Kf + (tile<<12));
    uint4* vd = (uint4*)(Vf + (tile<<12));
    kd[tid]       = ks[tid];
    kd[tid + 256] = ks[tid + 256];
    vd[tid]       = vs[tid];
    vd[tid + 256] = vs[tid + 256];
  }
}

// ============================================================
// Main attention.  Grid 1024 = 4 blocks/CU (16 waves/CU), 128 q rows
// per block (mb=2).  DMA double-buffer staging, fragment-linear LDS
// (conflict-free), XCD-aware swizzle, mask staged once as f32 bias in
// LDS, l via ones-MFMA, register-only P transform, s_setprio around
// MFMA clusters.  Measured 56us (R4).
// ============================================================
template<int USE_TAB>
__global__ __launch_bounds__(256,4) void attn8_kernel(
    const float* __restrict__ xq, const u16* __restrict__ Kf,
    const u16* __restrict__ Vf, const int* __restrict__ vis,
    const float2* __restrict__ tab, float* __restrict__ out)
{
  __shared__ u16 KV[2][2][4096];    // [buf][K/V][frag-linear], 32 KiB
  __shared__ float biasS[Nn];       // key-bias 0 / -1e30, 4 KiB

  const int tid  = threadIdx.x;
  const int lane = tid & 63;
  const int wave = tid >> 6;
  const int l15  = lane & 15;
  const int quad = lane >> 4;

  // ---- XCD-aware block decode (grid = 1024, 8 XCDs, 128 blocks/XCD) ----
  const int bid = blockIdx.x;
  const int xcd = bid & 7;          // consecutive bids round-robin XCDs
  const int ix  = bid >> 3;         // 0..127 within this XCD
  const int bh_ = (xcd<<4) | (ix>>3);  // 16 bh per XCD, 8 qt-blocks adjacent
  const int qt  = ix & 7;
  const int h   = bh_ & 7;
  const int b   = bh_ >> 3;
  const size_t bh = (size_t)bh_;
  const int qbase = qt<<7;          // 128 q rows per block

  const int* visb = vis + b*Nn;
  const u16* Kfb = Kf + (bh<<16);   // 16 tiles * 4096
  const u16* Vfb = Vf + (bh<<16);

  // ---- stage vis -> f32 bias in LDS (once) ----
  {
    int4 vi = *(const int4*)&visb[tid<<2];
    float4 bs;
    bs.x = vi.x ? 0.f : NEGBIG;
    bs.y = vi.y ? 0.f : NEGBIG;
    bs.z = vi.z ? 0.f : NEGBIG;
    bs.w = vi.w ? 0.f : NEGBIG;
    *(float4*)&biasS[tid<<2] = bs;
  }

  // ---- roped Q B-frags in registers (QS folded), 2 m-blocks ----
  short8 qa[2][2];
  #pragma unroll
  for (int mb=0; mb<2; ++mb){
    int n = qbase + (wave<<5) + (mb<<4) + l15;
    const float* src = xq + ((((size_t)b*Nn + n)*Hh + h)<<6);
    #pragma unroll
    for (int half=0; half<2; ++half){
      int d0 = (half<<5) + (quad<<3);
      const float4* g = (const float4*)(src + d0);
      float4 u0 = g[0], u1 = g[1];
      float xx[8] = {u0.x,u0.y,u0.z,u0.w, u1.x,u1.y,u1.z,u1.w};
      uint32_t w[4];
      #pragma unroll
      for (int j=0;j<4;++j){
        int i2 = (d0>>1) + j;
        float cs, sn;
        if (USE_TAB){
          float2 t = tab[(n<<5)+i2]; cs = t.x; sn = t.y;
        } else {
          float inv = exp2f(-(float)i2 * ROPE_K);
          sincosf((float)n * inv, &sn, &cs);
        }
        float x0 = xx[2*j], x1 = xx[2*j+1];
        float q0 = (x0*cs - x1*sn)*QS;
        float q1 = (x1*cs + x0*sn)*QS;
        w[j] = f2bf(q0) | (f2bf(q1)<<16);
      }
      U4S8 t; t.u = make_uint4(w[0],w[1],w[2],w[3]);
      qa[mb][half] = t.s;
    }
  }

  U4S8 ones_u; ones_u.u = make_uint4(0x3F803F80u,0x3F803F80u,0x3F803F80u,0x3F803F80u);
  const short8 ones = ones_u.s;

  f32x4 acc[2][4];                  // [mb][d-block]
  f32x4 l_acc[2];
  #pragma unroll
  for (int mb=0;mb<2;++mb){
    l_acc[mb] = (f32x4){0.f,0.f,0.f,0.f};
    #pragma unroll
    for (int s=0;s<4;++s) acc[mb][s] = (f32x4){0.f,0.f,0.f,0.f};
  }

  const int t8 = tid<<3;            // elem offset = tid*16B

  // ---- stage kt=0 into buf 0 ----
  gl_lds16(Kfb + t8,        &KV[0][0][t8]);
  gl_lds16(Kfb + 2048 + t8, &KV[0][0][2048 + t8]);
  gl_lds16(Vfb + t8,        &KV[0][1][t8]);
  gl_lds16(Vfb + 2048 + t8, &KV[0][1][2048 + t8]);
  __syncthreads();

  for (int kt=0; kt<16; ++kt){
    const int cur = kt & 1;
    // ---- issue async stage of kt+1 into the other buffer ----
    if (kt < 15){
      const u16* kg = Kfb + ((kt+1)<<12);
      const u16* vg = Vfb + ((kt+1)<<12);
      gl_lds16(kg + t8,        &KV[cur^1][0][t8]);
      gl_lds16(kg + 2048 + t8, &KV[cur^1][0][2048 + t8]);
      gl_lds16(vg + t8,        &KV[cur^1][1][t8]);
      gl_lds16(vg + 2048 + t8, &KV[cur^1][1][2048 + t8]);
    }

    // ---- S^T = K Q^T per kb (bias C-init = mask), exp2+pack in-register ----
    uint32_t pk[4][2][2];           // [kb][h][mb]
    __builtin_amdgcn_s_setprio(1);
    #pragma unroll
    for (int kb=0;kb<4;++kb){
      short8 kf0 = *(const short8*)&KV[cur][0][(kb<<10) + (lane<<3)];
      short8 kf1 = *(const short8*)&KV[cur][0][(kb<<10) + 512 + (lane<<3)];
      f32x4 bias = *(const f32x4*)&biasS[(kt<<6)+(kb<<4)+(quad<<2)];
      #pragma unroll
      for (int mb=0;mb<2;++mb){
        f32x4 t = mfma16(kf0, qa[mb][0], bias);
        t = mfma16(kf1, qa[mb][1], t);
        // lane holds S^T[key=kb*16+quad*4+rr][q=mb*16+l15], log2-domain
        float p0 = __builtin_amdgcn_exp2f(t.x);
        float p1 = __builtin_amdgcn_exp2f(t.y);
        float p2 = __builtin_amdgcn_exp2f(t.z);
        float p3 = __builtin_amdgcn_exp2f(t.w);
        BF2U e0; e0.h = __float22bfloat162_rn(make_float2(p0,p1));
        BF2U e1; e1.h = __float22bfloat162_rn(make_float2(p2,p3));
        pk[kb][0][mb] = e0.u;
        pk[kb][1][mb] = e1.u;
      }
    }
    __builtin_amdgcn_s_setprio(0);

    // ---- assemble P A-frags (pure register repack) ----
    short8 pa[2][2];
    #pragma unroll
    for (int mb=0;mb<2;++mb){
      U4S8 a0; a0.u = make_uint4(pk[0][0][mb], pk[1][0][mb], pk[2][0][mb], pk[3][0][mb]);
      U4S8 a1; a1.u = make_uint4(pk[0][1][mb], pk[1][1][mb], pk[2][1][mb], pk[3][1][mb]);
      pa[mb][0] = a0.s; pa[mb][1] = a1.s;
    }

    // ---- l += P * ones (matrix pipe), O += P V ----
    __builtin_amdgcn_s_setprio(1);
    #pragma unroll
    for (int mb=0;mb<2;++mb){
      l_acc[mb] = mfma16(pa[mb][0], ones, l_acc[mb]);
      l_acc[mb] = mfma16(pa[mb][1], ones, l_acc[mb]);
    }
    #pragma unroll
    for (int s=0;s<4;++s){
      short8 vb0 = *(const short8*)&KV[cur][1][(s<<10) + (lane<<3)];
      short8 vb1 = *(const short8*)&KV[cur][1][(s<<10) + 512 + (lane<<3)];
      #pragma unroll
      for (int mb=0;mb<2;++mb){
        acc[mb][s] = mfma16(pa[mb][0], vb0, acc[mb][s]);
        acc[mb][s] = mfma16(pa[mb][1], vb1, acc[mb][s]);
      }
    }
    __builtin_amdgcn_s_setprio(0);

    __syncthreads();  // drains kt+1 loads (issued a full compute phase ago)
  }

  // ---- epilogue: l already per-q in C layout; normalize + store ----
  #pragma unroll
  for (int mb=0;mb<2;++mb){
    #pragma unroll
    for (int rr=0;rr<4;++rr){
      int qrow = qbase + (wave<<5) + (mb<<4) + (quad<<2) + rr;
      float lq = l_acc[mb][rr];
      float invl = (biasS[qrow] == 0.f && lq > 0.f) ? 1.f/lq : 0.f;
      float* ob = out + ((((size_t)b*Nn + qrow)*Hh + h)<<6);
      #pragma unroll
      for (int s=0;s<4;++s)
        ob[(s<<4)+l15] = acc[mb][s][rr]*invl;
    }
  }
}

// ============================================================
// Fallback (inline sincos) — used if ws too small
// ============================================================
__device__ __forceinline__ void stage_rope_row_fb(const float* __restrict__ src,
                                                  u16 (*dst)[72],
                                                  int n_global, int sr, int d0)
{
  const float4* g = (const float4*)src;
  float4 a0 = g[0], a1 = g[1], a2 = g[2], a3 = g[3];
  float xx[16] = {a0.x,a0.y,a0.z,a0.w, a1.x,a1.y,a1.z,a1.w,
                  a2.x,a2.y,a2.z,a2.w, a3.x,a3.y,a3.z,a3.w};
  uint32_t w[8];
  #pragma unroll
  for (int j=0;j<8;++j){
    int i = (d0>>1)+j;
    float inv = exp2f(-(float)i * ROPE_K);
    float ang = (float)n_global * inv;
    float sn, cs; sincosf(ang, &sn, &cs);
    float x0 = xx[2*j], x1 = xx[2*j+1];
    float q0 = x0*cs - x1*sn;
    float q1 = x1*cs + x0*sn;
    w[j] = f2bf(q0) | (f2bf(q1)<<16);
  }
  *(uint4*)&dst[sr][d0]   = make_uint4(w[0],w[1],w[2],w[3]);
  *(uint4*)&dst[sr][d0+8] = make_uint4(w[4],w[5],w[6],w[7]);
}

__global__ __launch_bounds__(256,2) void attn_fallback(
    const float* __restrict__ xq, const float* __restrict__ xk,
    const float* __restrict__ xv, const int* __restrict__ vis,
    float* __restrict__ out)
{
  __shared__ u16 Qs[64][72];
  __shared__ u16 Ks[64][72];
  __shared__ u16 Vt[64][72];
  __shared__ u16 Ps[4][16][72];
  __shared__ float viss[64];

  const int tid  = threadIdx.x;
  const int wave = tid >> 6;
  const int lane = tid & 63;
  const int l15  = lane & 15;
  const int quad = lane >> 4;

  const int bid = blockIdx.x;
  const int qt = bid & 15;
  const int h  = (bid >> 4) & 7;
  const int b  = bid >> 7;

  const int sr = tid >> 2;
  const int d0 = (tid & 3) << 4;

  {
    int ng = (qt<<6) + sr;
    const float* src = xq + ((((size_t)b*Nn + ng)*Hh + h)<<6) + d0;
    stage_rope_row_fb(src, Qs, ng, sr, d0);
  }
  __syncthreads();

  short8 qa0 = *(const short8*)&Qs[(wave<<4)+l15][quad<<3];
  short8 qa1 = *(const short8*)&Qs[(wave<<4)+l15][(quad<<3)+32];

  f32x4 acc[4];
  #pragma unroll
  for (int s=0;s<4;++s) acc[s] = (f32x4){0.f,0.f,0.f,0.f};
  float m_r[4], l_r[4];
  #pragma unroll
  for (int rr=0;rr<4;++rr){ m_r[rr] = -1e30f; l_r[rr] = 0.f; }

  for (int kt=0; kt<16; ++kt){
    __syncthreads();
    {
      int ng = (kt<<6) + sr;
      const float* src = xk + ((((size_t)b*Nn + ng)*Hh + h)<<6) + d0;
      stage_rope_row_fb(src, Ks, ng, sr, d0);
    }
    {
      int ng = (kt<<6) + sr;
      const float4* g = (const float4*)(xv + ((((size_t)b*Nn + ng)*Hh + h)<<6) + d0);
      float4 a0 = g[0], a1 = g[1], a2 = g[2], a3 = g[3];
      float vv16[16] = {a0.x,a0.y,a0.z,a0.w, a1.x,a1.y,a1.z,a1.w,
                        a2.x,a2.y,a2.z,a2.w, a3.x,a3.y,a3.z,a3.w};
      #pragma unroll
      for (int j=0;j<16;++j) Vt[d0+j][sr] = (u16)f2bf(vv16[j]);
    }
    if (tid < 64) viss[tid] = (vis[b*Nn + (kt<<6) + tid] != 0) ? 1.f : 0.f;
    __syncthreads();

    f32x4 s4[4];
    #pragma unroll
    for (int n=0;n<4;++n){
      short8 kb0 = *(const short8*)&Ks[(n<<4)+l15][quad<<3];
      short8 kb1 = *(const short8*)&Ks[(n<<4)+l15][(quad<<3)+32];
      f32x4 t = (f32x4){0.f,0.f,0.f,0.f};
      t = mfma16(qa0, kb0, t);
      t = mfma16(qa1, kb1, t);
      s4[n] = t;
    }
    float vv[4];
    #pragma unroll
    for (int n=0;n<4;++n) vv[n] = viss[(n<<4)+l15];

    float p[4][4];
    #pragma unroll
    for (int rr=0; rr<4; ++rr){
      float sc[4];
      #pragma unroll
      for (int n=0;n<4;++n) sc[n] = (vv[n] > 0.f) ? s4[n][rr]*0.125f : -1e30f;
      float tm = fmaxf(fmaxf(sc[0],sc[1]), fmaxf(sc[2],sc[3]));
      tm = fmaxf(tm, __shfl_xor(tm,1));
      tm = fmaxf(tm, __shfl_xor(tm,2));
      tm = fmaxf(tm, __shfl_xor(tm,4));
      tm = fmaxf(tm, __shfl_xor(tm,8));
      float mnew  = fmaxf(m_r[rr], tm);
      float alpha = __expf(m_r[rr] - mnew);
      m_r[rr] = mnew;
      float psum = 0.f;
      #pragma unroll
      for (int n=0;n<4;++n){
        float pv = (vv[n] > 0.f) ? __expf(sc[n] - mnew) : 0.f;
        p[n][rr] = pv; psum += pv;
      }
      l_r[rr] = l_r[rr]*alpha + psum;
      #pragma unroll
      for (int s=0;s<4;++s) acc[s][rr] *= alpha;
    }

    #pragma unroll
    for (int n=0;n<4;++n)
      #pragma unroll
      for (int rr=0;rr<4;++rr)
        Ps[wave][(quad<<2)+rr][(n<<4)+l15] = (u16)f2bf(p[n][rr]);
    asm volatile("s_waitcnt lgkmcnt(0)" ::: "memory");
    short8 pa0 = *(const short8*)&Ps[wave][l15][quad<<3];
    short8 pa1 = *(const short8*)&Ps[wave][l15][(quad<<3)+32];

    #pragma unroll
    for (int s=0;s<4;++s){
      short8 vb0 = *(const short8*)&Vt[(s<<4)+l15][quad<<3];
      short8 vb1 = *(const short8*)&Vt[(s<<4)+l15][(quad<<3)+32];
      acc[s] = mfma16(pa0, vb0, acc[s]);
      acc[s] = mfma16(pa1, vb1, acc[s]);
    }
  }

  #pragma unroll
  for (int rr=0;rr<4;++rr){
    float t = l_r[rr];
    t += __shfl_xor(t,1); t += __shfl_xor(t,2);
    t += __shfl_xor(t,4); t += __shfl_xor(t,8);
    int row = (qt<<6) + (wave<<4) + (quad<<2) + rr;
    int qv  = vis[b*Nn + row];
    float invl = (qv != 0 && t > 0.f) ? 1.f/t : 0.f;
    size_t obase = (((size_t)b*Nn + row)*Hh + h) << 6;
    #pragma unroll
    for (int s=0;s<4;++s)
      out[obase + (s<<4) + l15] = acc[s][rr]*invl;
  }
}

extern "C" void kernel_launch(void* const* d_in, const int* in_sizes, int n_in,
                              void* d_out, int out_size, void* d_ws, size_t ws_size,
                              hipStream_t stream)
{
  const float* xq = (const float*)d_in[0];
  const float* xk = (const float*)d_in[1];
  const float* xv = (const float*)d_in[2];
  const int* vis  = (const int*)d_in[3];
  float* out = (float*)d_out;

  const size_t kv_elems = (size_t)Bb*Hh*Nn*Dd;            // 8.39M
  const size_t kv_bytes = kv_elems*sizeof(u16);           // 16.78 MB
  const size_t need_kv  = 2*kv_bytes;                     // 33.6 MB
  const size_t tab_bytes = (size_t)32*1024*sizeof(float2);// 256 KB

  if (d_ws != nullptr && ws_size >= need_kv + tab_bytes){
    u16* Kf = (u16*)d_ws;
    u16* Vf = Kf + kv_elems;
    float2* tab = (float2*)((char*)d_ws + need_kv);
    rope_table_kernel<<<dim3(128), dim3(256), 0, stream>>>(tab);
    prepass_kernel<1><<<dim3(Bb*Hh*(Nn/64)), dim3(256), 0, stream>>>(xk, xv, Kf, Vf, tab);
    attn8_kernel<1><<<dim3(Bb*Hh*(Nn/128)), dim3(256), 0, stream>>>(xq, Kf, Vf, vis, tab, out);
  } else if (d_ws != nullptr && ws_size >= need_kv){
    u16* Kf = (u16*)d_ws;
    u16* Vf = Kf + kv_elems;
    prepass_kernel<0><<<dim3(Bb*Hh*(Nn/64)), dim3(256), 0, stream>>>(xk, xv, Kf, Vf, nullptr);
    attn8_kernel<0><<<dim3(Bb*Hh*(Nn/128)), dim3(256), 0, stream>>>(xq, Kf, Vf, vis, nullptr, out);
  } else {
    attn_fallback<<<dim3(Bb*Hh*(Nn/64)), dim3(256), 0, stream>>>(xq, xk, xv, vis, out);
  }
}